// Round 9
// baseline (363.040 us; speedup 1.0000x reference)
//
#include <hip/hip_runtime.h>
#include <stdint.h>

typedef unsigned short ushort_t;
typedef __attribute__((ext_vector_type(8))) short bf16x8;   // 8 bf16 = 4 VGPRs
typedef __attribute__((ext_vector_type(4))) float f32x4;

__device__ __forceinline__ ushort_t f2bf(float f) {
  union { float f; unsigned u; } v; v.f = f;
  unsigned r = v.u + 0x7fffu + ((v.u >> 16) & 1u);
  return (ushort_t)(r >> 16);
}
__device__ __forceinline__ unsigned bfbits(float f) {
  union { float f; unsigned u; } v; v.f = f; return v.u;
}
// pack two floats' bf16 truncations: [hi.bf16 : lo.bf16] (v_perm_b32:
// sel bytes 0-3 <- src1, 4-7 <- src0; 0x07060302 = {lo[2],lo[3],hi[2],hi[3]})
__device__ __forceinline__ unsigned pack_trunc(float lo, float hi) {
#if __has_builtin(__builtin_amdgcn_perm)
  return __builtin_amdgcn_perm(bfbits(hi), bfbits(lo), 0x07060302u);
#else
  return (bfbits(lo) >> 16) | (bfbits(hi) & 0xffff0000u);
#endif
}
__device__ __forceinline__ unsigned pack_rn(float lo, float hi) {
  return (unsigned)f2bf(lo) | ((unsigned)f2bf(hi) << 16);
}

#define SCALE_Q 0.18033688011112042f   /* 0.125 * log2(e) */
#define EXP_BIAS 23.083109273961734f   /* 16 * log2(e) */

// ---------- GroupNorm stats stage 1: 256 blocks x 16384 floats -------------
__global__ __launch_bounds__(256)
void gn_stats1(const float* __restrict__ x, float2* __restrict__ partial) {
  int blk = blockIdx.x, tid = threadIdx.x;
  const float* base = x + (size_t)blk * 16384;
  float s = 0.f, ss = 0.f;
  for (int i = tid * 4; i < 16384; i += 1024) {
    float4 v = *(const float4*)(base + i);
    s  += v.x + v.y + v.z + v.w;
    ss += v.x*v.x + v.y*v.y + v.z*v.z + v.w*v.w;
  }
  __shared__ float rs[256], rss[256];
  rs[tid] = s; rss[tid] = ss;
  __syncthreads();
  for (int off = 128; off > 0; off >>= 1) {
    if (tid < off) { rs[tid] += rs[tid+off]; rss[tid] += rss[tid+off]; }
    __syncthreads();
  }
  if (tid == 0) partial[blk] = make_float2(rs[0], rss[0]);
}

// ---------- GroupNorm stats stage 2: reduce 8 partials per (b,g) -----------
__global__ __launch_bounds__(64)
void gn_stats2(const float2* __restrict__ partial, float* __restrict__ stats) {
  int g = threadIdx.x;
  if (g < 32) {
    float s = 0.f, ss = 0.f;
    #pragma unroll
    for (int k = 0; k < 8; k++) { float2 p = partial[g*8 + k]; s += p.x; ss += p.y; }
    float mean = s * (1.f/131072.f);
    float var  = ss * (1.f/131072.f) - mean*mean;
    stats[g*2]   = mean;
    stats[g*2+1] = rsqrtf(var + 1e-5f);
  }
}

// -- normalize+transpose: x[b][c][n] -> xn_t[(b-b0)*4096+n][c] (bf16 chunk) -
__global__ __launch_bounds__(256)
void gn_apply_t(const float* __restrict__ x, const float* __restrict__ stats,
                const float* __restrict__ gamma, const float* __restrict__ beta,
                ushort_t* __restrict__ xn_t, int b0) {
  int blk = blockIdx.x;            // nb*128 = bl x nt(16) x ct(8)
  int tid = threadIdx.x;
  int ct = blk & 7;
  int nt = (blk >> 3) & 15;
  int bl = blk >> 7;               // local batch in chunk
  int b  = b0 + bl;                // global batch
  int c0 = ct * 32;                // one 32-ch group per tile (group == ct)
  float mean = stats[(b*8 + ct)*2];
  float rstd = stats[(b*8 + ct)*2 + 1];
  __shared__ ushort_t Ls[32][264];
  for (int idx = tid; idx < 32*64; idx += 256) {
    int cc = idx >> 6, seg = idx & 63;
    float ga = gamma[c0+cc], be = beta[c0+cc];
    float a = rstd * ga;
    float bb = be - mean * a;
    float4 v = *(const float4*)(x + ((size_t)(b*256 + c0 + cc))*4096 + nt*256 + seg*4);
    ushort4 t4 = make_ushort4(f2bf(v.x*a+bb), f2bf(v.y*a+bb), f2bf(v.z*a+bb), f2bf(v.w*a+bb));
    *(ushort4*)&Ls[cc][seg*4] = t4;
  }
  __syncthreads();
  for (int idx = tid; idx < 256*4; idx += 256) {
    int n = idx >> 2, seg = idx & 3;
    union { ushort_t u[8]; uint4 v; } pk;
    #pragma unroll
    for (int e = 0; e < 8; e++) pk.u[e] = Ls[seg*8 + e][n];
    *(uint4*)(xn_t + ((size_t)(bl*4096 + nt*256 + n))*256 + c0 + seg*8) = pk.v;
  }
}

// ------- fp32 -> bf16 weight convert, both weight tensors in one launch ----
__global__ __launch_bounds__(256)
void wconv2(const float* __restrict__ wq, const float* __restrict__ wp,
            ushort_t* __restrict__ oq, ushort_t* __restrict__ op) {
  int blk = blockIdx.x;            // 0-191: qkv (196608), 192-255: proj (65536)
  const float* w; ushort_t* o; int i;
  if (blk < 192) { w = wq; o = oq; i = blk*256 + threadIdx.x; }
  else           { w = wp; o = op; i = (blk-192)*256 + threadIdx.x; }
  float4 v = *(const float4*)(w + (size_t)i*4);
  *(ushort4*)(o + (size_t)i*4) = make_ushort4(f2bf(v.x), f2bf(v.y), f2bf(v.z), f2bf(v.w));
}

// ------- GEMM1: tile 128M x 64N. Q->q[tok][256] (scaled), K->k[tok][256],
//         V -> vt[b*4+h][d][tok] (transposed through LDS, one head/tile).
__global__ __launch_bounds__(256)
void gemm_qkv(const ushort_t* __restrict__ A, const ushort_t* __restrict__ Bt,
              const float* __restrict__ bias, ushort_t* __restrict__ q,
              ushort_t* __restrict__ kbuf, ushort_t* __restrict__ vt, int b0) {
  int blk = blockIdx.x;            // (nb*32)*12 = mt x nt(12)
  int nt = blk % 12, mt = blk / 12;
  int m0 = mt*128, n0 = nt*64;
  int tid = threadIdx.x;
  int wave = tid >> 6, lane = tid & 63, quad = lane >> 4, l16 = lane & 15;
  __shared__ ushort_t As[128][40];
  __shared__ ushort_t Bs[64][40];
  __shared__ ushort_t Lt[64][136];   // V transpose tile [d][tok]
  f32x4 acc[2][4];
  #pragma unroll
  for (int i = 0; i < 2; i++)
    #pragma unroll
    for (int j = 0; j < 4; j++) acc[i][j] = (f32x4){0.f,0.f,0.f,0.f};

  for (int k0 = 0; k0 < 256; k0 += 32) {
    #pragma unroll
    for (int i = tid; i < 512; i += 256) {
      int row = i >> 2, seg = i & 3;
      *(uint4*)&As[row][seg*8] = *(const uint4*)(A + (size_t)(m0+row)*256 + k0 + seg*8);
    }
    {
      int row = tid >> 2, seg = tid & 3;
      *(uint4*)&Bs[row][seg*8] = *(const uint4*)(Bt + (size_t)(n0+row)*256 + k0 + seg*8);
    }
    __syncthreads();
    bf16x8 af[2], bfr[4];
    #pragma unroll
    for (int t = 0; t < 2; t++) af[t]  = *(const bf16x8*)&As[wave*32 + t*16 + l16][quad*8];
    #pragma unroll
    for (int t = 0; t < 4; t++) bfr[t] = *(const bf16x8*)&Bs[t*16 + l16][quad*8];
    #pragma unroll
    for (int ti = 0; ti < 2; ti++)
      #pragma unroll
      for (int jn = 0; jn < 4; jn++)
        acc[ti][jn] = __builtin_amdgcn_mfma_f32_16x16x32_bf16(af[ti], bfr[jn], acc[ti][jn], 0, 0, 0);
    __syncthreads();
  }

  int region = nt >> 2;   // 0=Q (n<256), 1=K, 2=V
  if (region == 0) {
    #pragma unroll
    for (int jn = 0; jn < 4; jn++) {
      int n = n0 + jn*16 + l16;
      float bv = bias[n];
      #pragma unroll
      for (int ti = 0; ti < 2; ti++) {
        int mrow = m0 + wave*32 + ti*16 + quad*4;
        #pragma unroll
        for (int r = 0; r < 4; r++)
          q[(size_t)(b0*4096 + mrow + r)*256 + n] = f2bf((acc[ti][jn][r] + bv) * SCALE_Q);
      }
    }
  } else if (region == 1) {
    #pragma unroll
    for (int jn = 0; jn < 4; jn++) {
      int n = n0 + jn*16 + l16;
      float bv = bias[n];
      #pragma unroll
      for (int ti = 0; ti < 2; ti++) {
        int mrow = m0 + wave*32 + ti*16 + quad*4;
        #pragma unroll
        for (int r = 0; r < 4; r++)
          kbuf[(size_t)(b0*4096 + mrow + r)*256 + (n - 256)] = f2bf(acc[ti][jn][r] + bv);
      }
    }
  } else {
    int hh = nt - 8;                 // one head per 64-wide tile
    int b_loc = m0 >> 12;
    #pragma unroll
    for (int jn = 0; jn < 4; jn++) {
      int n = n0 + jn*16 + l16;
      float bv = bias[n];
      int drow = jn*16 + l16;        // d within head (0..63)
      #pragma unroll
      for (int ti = 0; ti < 2; ti++) {
        int tcol = wave*32 + ti*16 + quad*4;
        uint2 w;
        w.x = pack_rn(acc[ti][jn][0] + bv, acc[ti][jn][1] + bv);
        w.y = pack_rn(acc[ti][jn][2] + bv, acc[ti][jn][3] + bv);
        *(uint2*)&Lt[drow][tcol] = w;
      }
    }
    __syncthreads();
    size_t vb_ = ((size_t)((b0 + b_loc)*4 + hh)*64)*4096 + (size_t)(m0 & 4095);
    for (int idx = tid; idx < 1024; idx += 256) {
      int dd = idx >> 4, toff = (idx & 15)*8;
      *(uint4*)(vt + vb_ + (size_t)dd*4096 + toff) = *(const uint4*)&Lt[dd][toff];
    }
  }
}

// -------- flash attention v6: 128-key tiles (2 barriers/128 keys),
//          single-buffer K/V + register prefetch, slim Ps, v_perm pack.
// q[tok][256] (pre-scaled by 0.125*log2e), k[tok][256], vt[bh][d][tok].
// O overwrites q in place (disjoint rows/cols per block -> race-free).
__global__ __launch_bounds__(256)
void attn(ushort_t* __restrict__ q, const ushort_t* __restrict__ k,
          const ushort_t* __restrict__ vt) {
  int blk = blockIdx.x;            // nb*128 = bl x h(4) x it(32)
  int it = blk & 31;
  int h  = (blk >> 5) & 3;
  int b  = blk >> 7;
  int i0 = it * 128;
  int tid = threadIdx.x;
  int wave = tid >> 6, lane = tid & 63, quad = lane >> 4, l16 = lane & 15;

  __shared__ ushort_t Ks[128][72];    // [j][d]
  __shared__ ushort_t Vs[64][136];    // [d][j]
  __shared__ ushort_t Ps[4][16][72];  // per-wave P tile [i(16)][j(64)]

  ushort_t* qbase = q + (size_t)(b*4096 + i0)*256 + h*64;
  const ushort_t* kbase = k + (size_t)(b*4096)*256 + h*64;
  const ushort_t* vbase = vt + (size_t)(b*4 + h)*64*4096;

  // Q fragments direct from global: row wave*32+t*16+l16, col kk*32+quad*8
  bf16x8 qa[2][2];
  #pragma unroll
  for (int t = 0; t < 2; t++)
    #pragma unroll
    for (int kk = 0; kk < 2; kk++) {
      uint4 u = *(const uint4*)(qbase + (size_t)(wave*32 + t*16 + l16)*256 + kk*32 + quad*8);
      qa[t][kk] = *(const bf16x8*)&u;
    }

  bf16x8 ones;
  #pragma unroll
  for (int e = 0; e < 8; e++) ones[e] = (short)0x3F80;   // bf16 1.0

  f32x4 o_acc[2][4];   // O^T frags: lane=i, reg=d
  f32x4 l_acc[2];
  #pragma unroll
  for (int t = 0; t < 2; t++) {
    l_acc[t] = (f32x4){0.f,0.f,0.f,0.f};
    #pragma unroll
    for (int d = 0; d < 4; d++) o_acc[t][d] = (f32x4){0.f,0.f,0.f,0.f};
  }

  int sj = tid >> 3, sseg = (tid & 7)*8;   // staging: sj in [0,32), sseg 8-col
  uint4 rk[4], rv[4];
  #define LOADT(JT) { int j0n = (JT)*128; \
    rk[0] = *(const uint4*)(kbase + (size_t)(j0n + sj      )*256 + sseg); \
    rk[1] = *(const uint4*)(kbase + (size_t)(j0n + sj + 32 )*256 + sseg); \
    rk[2] = *(const uint4*)(kbase + (size_t)(j0n + sj + 64 )*256 + sseg); \
    rk[3] = *(const uint4*)(kbase + (size_t)(j0n + sj + 96 )*256 + sseg); \
    rv[0] = *(const uint4*)(vbase + (size_t)(sj     )*4096 + j0n + sseg); \
    rv[1] = *(const uint4*)(vbase + (size_t)(sj     )*4096 + j0n + 64 + sseg); \
    rv[2] = *(const uint4*)(vbase + (size_t)(sj + 32)*4096 + j0n + sseg); \
    rv[3] = *(const uint4*)(vbase + (size_t)(sj + 32)*4096 + j0n + 64 + sseg); }
  #define WRITET() { \
    *(uint4*)&Ks[sj      ][sseg] = rk[0]; \
    *(uint4*)&Ks[sj + 32 ][sseg] = rk[1]; \
    *(uint4*)&Ks[sj + 64 ][sseg] = rk[2]; \
    *(uint4*)&Ks[sj + 96 ][sseg] = rk[3]; \
    *(uint4*)&Vs[sj     ][sseg] = rv[0]; \
    *(uint4*)&Vs[sj     ][64 + sseg] = rv[1]; \
    *(uint4*)&Vs[sj + 32][sseg] = rv[2]; \
    *(uint4*)&Vs[sj + 32][64 + sseg] = rv[3]; }

  LOADT(0); WRITET();
  __syncthreads();

  for (int jt = 0; jt < 32; jt++) {
    if (jt < 31) LOADT(jt + 1);    // next 128-key tile in flight

    #pragma unroll
    for (int sub = 0; sub < 2; sub++) {
      int jb = sub * 64;
      bf16x8 kb[4][2], vb[4][2];
      #pragma unroll
      for (int jn = 0; jn < 4; jn++)
        #pragma unroll
        for (int kk = 0; kk < 2; kk++) {
          kb[jn][kk] = *(const bf16x8*)&Ks[jb + jn*16 + l16][kk*32 + quad*8];
          vb[jn][kk] = *(const bf16x8*)&Vs[jn*16 + l16][jb + kk*32 + quad*8];
        }

      #pragma unroll
      for (int t = 0; t < 2; t++) {
        // S^T frags: C[j=quad*4+r][i=l16]; acc pre-biased with -16*log2e
        f32x4 s[4];
        #pragma unroll
        for (int jn = 0; jn < 4; jn++) {
          f32x4 a4 = (f32x4){-EXP_BIAS, -EXP_BIAS, -EXP_BIAS, -EXP_BIAS};
          #pragma unroll
          for (int kk = 0; kk < 2; kk++)
            a4 = __builtin_amdgcn_mfma_f32_16x16x32_bf16(kb[jn][kk], qa[t][kk], a4, 0, 0, 0);
          s[jn] = a4;
        }
        // exp, pack, b64 write: Ps[wave][i=l16][j=jn*16+quad*4..+3]
        #pragma unroll
        for (int jn = 0; jn < 4; jn++) {
          float p0 = __builtin_exp2f(s[jn][0]);
          float p1 = __builtin_exp2f(s[jn][1]);
          float p2 = __builtin_exp2f(s[jn][2]);
          float p3 = __builtin_exp2f(s[jn][3]);
          uint2 w;
          w.x = pack_trunc(p0, p1);
          w.y = pack_trunc(p2, p3);
          *(uint2*)&Ps[wave][l16][jn*16 + quad*4] = w;
        }
        // Ps wave-private: same-wave DS ordering (lgkmcnt) suffices.
        bf16x8 pa[2];
        #pragma unroll
        for (int kk = 0; kk < 2; kk++)
          pa[kk] = *(const bf16x8*)&Ps[wave][l16][kk*32 + quad*8];
        // PV + l
        #pragma unroll
        for (int dn = 0; dn < 4; dn++)
          #pragma unroll
          for (int kk = 0; kk < 2; kk++)
            o_acc[t][dn] = __builtin_amdgcn_mfma_f32_16x16x32_bf16(vb[dn][kk], pa[kk], o_acc[t][dn], 0, 0, 0);
        #pragma unroll
        for (int kk = 0; kk < 2; kk++)
          l_acc[t] = __builtin_amdgcn_mfma_f32_16x16x32_bf16(ones, pa[kk], l_acc[t], 0, 0, 0);
      }
    }

    if (jt < 31) {
      __syncthreads();             // all waves done reading Ks/Vs
      WRITET();                    // tile jt+1
      __syncthreads();             // visible
    }
  }
  #undef LOADT
  #undef WRITET

  // O^T frag: lane l16 = i, quad*4+r = d -> 4 contiguous d = b64 store
  #pragma unroll
  for (int t = 0; t < 2; t++) {
    float inv = 1.f / l_acc[t][0];
    size_t row = (size_t)(b*4096 + i0 + wave*32 + t*16 + l16)*256 + h*64;
    #pragma unroll
    for (int dn = 0; dn < 4; dn++) {
      ushort4 u;
      u.x = f2bf(o_acc[t][dn][0]*inv); u.y = f2bf(o_acc[t][dn][1]*inv);
      u.z = f2bf(o_acc[t][dn][2]*inv); u.w = f2bf(o_acc[t][dn][3]*inv);
      *(ushort4*)(q + row + dn*16 + quad*4) = u;
    }
  }
}

// - GEMM2: tile 128M x 64N. out[col][o] = sum_c wp[o][c]*O[col][c]+bias+resid
// O lives in q buffer, stride 256.
__global__ __launch_bounds__(256)
void gemm_proj(const ushort_t* __restrict__ A,    // wproj_bf [256][256]
               const ushort_t* __restrict__ Bt,   // q (O) [*][256]
               const float* __restrict__ bias, const float* __restrict__ resid,
               float* __restrict__ out, int col_base) {
  int blk = blockIdx.x;            // nb*128 = mt(2) x nt(nb*64)
  int mt = blk & 1, nt = blk >> 1;
  int m0 = mt*128, n0 = nt*64;
  int tid = threadIdx.x;
  int wave = tid >> 6, lane = tid & 63, quad = lane >> 4, l16 = lane & 15;
  __shared__ ushort_t As[128][40];
  __shared__ ushort_t Bs[64][40];
  f32x4 acc[2][4];
  #pragma unroll
  for (int i = 0; i < 2; i++)
    #pragma unroll
    for (int j = 0; j < 4; j++) acc[i][j] = (f32x4){0.f,0.f,0.f,0.f};

  for (int k0 = 0; k0 < 256; k0 += 32) {
    #pragma unroll
    for (int i = tid; i < 512; i += 256) {
      int row = i >> 2, seg = i & 3;
      *(uint4*)&As[row][seg*8] = *(const uint4*)(A + (size_t)(m0+row)*256 + k0 + seg*8);
    }
    {
      int row = tid >> 2, seg = tid & 3;
      *(uint4*)&Bs[row][seg*8] = *(const uint4*)(Bt + (size_t)(n0+row)*256 + k0 + seg*8);
    }
    __syncthreads();
    bf16x8 af[2], bfr[4];
    #pragma unroll
    for (int t = 0; t < 2; t++) af[t]  = *(const bf16x8*)&As[wave*32 + t*16 + l16][quad*8];
    #pragma unroll
    for (int t = 0; t < 4; t++) bfr[t] = *(const bf16x8*)&Bs[t*16 + l16][quad*8];
    #pragma unroll
    for (int ti = 0; ti < 2; ti++)
      #pragma unroll
      for (int jn = 0; jn < 4; jn++)
        acc[ti][jn] = __builtin_amdgcn_mfma_f32_16x16x32_bf16(af[ti], bfr[jn], acc[ti][jn], 0, 0, 0);
    __syncthreads();
  }
  #pragma unroll
  for (int jn = 0; jn < 4; jn++) {
    int col = col_base + n0 + jn*16 + l16;
    int bb = col >> 12;
    int np = col & 4095;
    #pragma unroll
    for (int ti = 0; ti < 2; ti++) {
      int o = m0 + wave*32 + ti*16 + quad*4;
      #pragma unroll
      for (int r = 0; r < 4; r++) {
        int oo = o + r;
        size_t addr = ((size_t)(bb*256 + oo))*4096 + np;
        out[addr] = acc[ti][jn][r] + bias[oo] + resid[addr];
      }
    }
  }
}

extern "C" void kernel_launch(void* const* d_in, const int* in_sizes, int n_in,
                              void* d_out, int out_size, void* d_ws, size_t ws_size,
                              hipStream_t stream) {
  const float* x      = (const float*)d_in[0];
  const float* gamma  = (const float*)d_in[1];
  const float* beta   = (const float*)d_in[2];
  const float* w_qkv  = (const float*)d_in[3];
  const float* b_qkv  = (const float*)d_in[4];
  const float* w_proj = (const float*)d_in[5];
  const float* b_proj = (const float*)d_in[6];
  float* out = (float*)d_out;

  char* ws = (char*)d_ws;
  float*  stats    = (float*)ws;                   // 256 B
  float2* partial  = (float2*)(ws + 1024);         // 2048 B
  ushort_t* wqkv_bf  = (ushort_t*)(ws + 4096);     // 393216 B
  ushort_t* wproj_bf = (ushort_t*)(ws + 397312);   // 131072 B
  char* big = ws + 528384;

  gn_stats1<<<dim3(256), dim3(256), 0, stream>>>(x, partial);
  gn_stats2<<<dim3(1), dim3(64), 0, stream>>>(partial, stats);
  wconv2<<<dim3(256), dim3(256), 0, stream>>>(w_qkv, w_proj, wqkv_bf, wproj_bf);

  // Full path: q 8.39M + k 8.39M + vt 8.39M + xn(nb=2) 4.19M = 29,888,512 B.
  if (ws_size >= (size_t)528384 + 3*(size_t)8388608 + (size_t)4194304) {
    ushort_t* q    = (ushort_t*)big;
    ushort_t* kbuf = (ushort_t*)(big + (size_t)8388608);
    ushort_t* vt   = (ushort_t*)(big + (size_t)16777216);
    ushort_t* xn   = (ushort_t*)(big + (size_t)25165824);
    for (int c = 0; c < 2; c++) {
      int b0 = c * 2;
      gn_apply_t<<<dim3(256), dim3(256), 0, stream>>>(x, stats, gamma, beta, xn, b0);
      gemm_qkv<<<dim3(768), dim3(256), 0, stream>>>(xn, wqkv_bf, b_qkv, q, kbuf, vt, b0);
    }
    attn<<<dim3(512), dim3(256), 0, stream>>>(q, kbuf, vt);
    gemm_proj<<<dim3(512), dim3(256), 0, stream>>>(wproj_bf, q, b_proj, x, out, 0);
  } else {
    // Per-batch fallback: 4 x 2.1M = 8.4M after fixed region.
    ushort_t* q_c  = (ushort_t*)big;
    ushort_t* k_c  = (ushort_t*)(big + (size_t)2097152);
    ushort_t* vt_c = (ushort_t*)(big + (size_t)4194304);
    ushort_t* xn_c = (ushort_t*)(big + (size_t)6291456);
    for (int b0 = 0; b0 < 4; b0++) {
      gn_apply_t<<<dim3(128), dim3(256), 0, stream>>>(x, stats, gamma, beta, xn_c, b0);
      gemm_qkv<<<dim3(384), dim3(256), 0, stream>>>(xn_c, wqkv_bf, b_qkv, q_c, k_c, vt_c, 0);
      attn<<<dim3(128), dim3(256), 0, stream>>>(q_c, k_c, vt_c);
      gemm_proj<<<dim3(128), dim3(256), 0, stream>>>(wproj_bf, q_c, b_proj, x, out, b0*4096);
    }
  }
}

// Round 10
// 291.876 us; speedup vs baseline: 1.2438x; 1.2438x over previous
//
#include <hip/hip_runtime.h>
#include <stdint.h>

typedef unsigned short ushort_t;
typedef __attribute__((ext_vector_type(8))) short bf16x8;   // 8 bf16 = 4 VGPRs
typedef __attribute__((ext_vector_type(4))) float f32x4;

__device__ __forceinline__ ushort_t f2bf(float f) {
  union { float f; unsigned u; } v; v.f = f;
  unsigned r = v.u + 0x7fffu + ((v.u >> 16) & 1u);
  return (ushort_t)(r >> 16);
}
__device__ __forceinline__ unsigned bfbits(float f) {
  union { float f; unsigned u; } v; v.f = f; return v.u;
}
// pack two floats' bf16 truncations: [hi.bf16 : lo.bf16] (v_perm_b32:
// sel bytes 0-3 <- src1, 4-7 <- src0; 0x07060302 = {lo[2],lo[3],hi[2],hi[3]})
__device__ __forceinline__ unsigned pack_trunc(float lo, float hi) {
#if __has_builtin(__builtin_amdgcn_perm)
  return __builtin_amdgcn_perm(bfbits(hi), bfbits(lo), 0x07060302u);
#else
  return (bfbits(lo) >> 16) | (bfbits(hi) & 0xffff0000u);
#endif
}
__device__ __forceinline__ unsigned pack_rn(float lo, float hi) {
  return (unsigned)f2bf(lo) | ((unsigned)f2bf(hi) << 16);
}

#define SCALE_Q 0.18033688011112042f   /* 0.125 * log2(e) */
#define EXP_BIAS 23.083109273961734f   /* 16 * log2(e) */

// ---------- GroupNorm stats stage 1: 256 blocks x 16384 floats -------------
__global__ __launch_bounds__(256)
void gn_stats1(const float* __restrict__ x, float2* __restrict__ partial) {
  int blk = blockIdx.x, tid = threadIdx.x;
  const float* base = x + (size_t)blk * 16384;
  float s = 0.f, ss = 0.f;
  for (int i = tid * 4; i < 16384; i += 1024) {
    float4 v = *(const float4*)(base + i);
    s  += v.x + v.y + v.z + v.w;
    ss += v.x*v.x + v.y*v.y + v.z*v.z + v.w*v.w;
  }
  __shared__ float rs[256], rss[256];
  rs[tid] = s; rss[tid] = ss;
  __syncthreads();
  for (int off = 128; off > 0; off >>= 1) {
    if (tid < off) { rs[tid] += rs[tid+off]; rss[tid] += rss[tid+off]; }
    __syncthreads();
  }
  if (tid == 0) partial[blk] = make_float2(rs[0], rss[0]);
}

// ---------- GroupNorm stats stage 2: reduce 8 partials per (b,g) -----------
__global__ __launch_bounds__(64)
void gn_stats2(const float2* __restrict__ partial, float* __restrict__ stats) {
  int g = threadIdx.x;
  if (g < 32) {
    float s = 0.f, ss = 0.f;
    #pragma unroll
    for (int k = 0; k < 8; k++) { float2 p = partial[g*8 + k]; s += p.x; ss += p.y; }
    float mean = s * (1.f/131072.f);
    float var  = ss * (1.f/131072.f) - mean*mean;
    stats[g*2]   = mean;
    stats[g*2+1] = rsqrtf(var + 1e-5f);
  }
}

// -- normalize+transpose: x[b][c][n] -> xn_t[(b-b0)*4096+n][c] (bf16 chunk) -
__global__ __launch_bounds__(256)
void gn_apply_t(const float* __restrict__ x, const float* __restrict__ stats,
                const float* __restrict__ gamma, const float* __restrict__ beta,
                ushort_t* __restrict__ xn_t, int b0) {
  int blk = blockIdx.x;            // nb*128 = bl x nt(16) x ct(8)
  int tid = threadIdx.x;
  int ct = blk & 7;
  int nt = (blk >> 3) & 15;
  int bl = blk >> 7;               // local batch in chunk
  int b  = b0 + bl;                // global batch
  int c0 = ct * 32;                // one 32-ch group per tile (group == ct)
  float mean = stats[(b*8 + ct)*2];
  float rstd = stats[(b*8 + ct)*2 + 1];
  __shared__ ushort_t Ls[32][264];
  for (int idx = tid; idx < 32*64; idx += 256) {
    int cc = idx >> 6, seg = idx & 63;
    float ga = gamma[c0+cc], be = beta[c0+cc];
    float a = rstd * ga;
    float bb = be - mean * a;
    float4 v = *(const float4*)(x + ((size_t)(b*256 + c0 + cc))*4096 + nt*256 + seg*4);
    ushort4 t4 = make_ushort4(f2bf(v.x*a+bb), f2bf(v.y*a+bb), f2bf(v.z*a+bb), f2bf(v.w*a+bb));
    *(ushort4*)&Ls[cc][seg*4] = t4;
  }
  __syncthreads();
  for (int idx = tid; idx < 256*4; idx += 256) {
    int n = idx >> 2, seg = idx & 3;
    union { ushort_t u[8]; uint4 v; } pk;
    #pragma unroll
    for (int e = 0; e < 8; e++) pk.u[e] = Ls[seg*8 + e][n];
    *(uint4*)(xn_t + ((size_t)(bl*4096 + nt*256 + n))*256 + c0 + seg*8) = pk.v;
  }
}

// ------- fp32 -> bf16 weight convert, both weight tensors in one launch ----
__global__ __launch_bounds__(256)
void wconv2(const float* __restrict__ wq, const float* __restrict__ wp,
            ushort_t* __restrict__ oq, ushort_t* __restrict__ op) {
  int blk = blockIdx.x;            // 0-191: qkv (196608), 192-255: proj (65536)
  const float* w; ushort_t* o; int i;
  if (blk < 192) { w = wq; o = oq; i = blk*256 + threadIdx.x; }
  else           { w = wp; o = op; i = (blk-192)*256 + threadIdx.x; }
  float4 v = *(const float4*)(w + (size_t)i*4);
  *(ushort4*)(o + (size_t)i*4) = make_ushort4(f2bf(v.x), f2bf(v.y), f2bf(v.z), f2bf(v.w));
}

// ------- GEMM1: tile 128M x 64N. Q->q[tok][256] (scaled), K->k[tok][256],
//         V -> vt[b*4+h][d][tok] (transposed through LDS, one head/tile).
__global__ __launch_bounds__(256)
void gemm_qkv(const ushort_t* __restrict__ A, const ushort_t* __restrict__ Bt,
              const float* __restrict__ bias, ushort_t* __restrict__ q,
              ushort_t* __restrict__ kbuf, ushort_t* __restrict__ vt, int b0) {
  int blk = blockIdx.x;            // (nb*32)*12 = mt x nt(12)
  int nt = blk % 12, mt = blk / 12;
  int m0 = mt*128, n0 = nt*64;
  int tid = threadIdx.x;
  int wave = tid >> 6, lane = tid & 63, quad = lane >> 4, l16 = lane & 15;
  __shared__ ushort_t As[128][40];
  __shared__ ushort_t Bs[64][40];
  __shared__ ushort_t Lt[64][136];   // V transpose tile [d][tok]
  f32x4 acc[2][4];
  #pragma unroll
  for (int i = 0; i < 2; i++)
    #pragma unroll
    for (int j = 0; j < 4; j++) acc[i][j] = (f32x4){0.f,0.f,0.f,0.f};

  for (int k0 = 0; k0 < 256; k0 += 32) {
    #pragma unroll
    for (int i = tid; i < 512; i += 256) {
      int row = i >> 2, seg = i & 3;
      *(uint4*)&As[row][seg*8] = *(const uint4*)(A + (size_t)(m0+row)*256 + k0 + seg*8);
    }
    {
      int row = tid >> 2, seg = tid & 3;
      *(uint4*)&Bs[row][seg*8] = *(const uint4*)(Bt + (size_t)(n0+row)*256 + k0 + seg*8);
    }
    __syncthreads();
    bf16x8 af[2], bfr[4];
    #pragma unroll
    for (int t = 0; t < 2; t++) af[t]  = *(const bf16x8*)&As[wave*32 + t*16 + l16][quad*8];
    #pragma unroll
    for (int t = 0; t < 4; t++) bfr[t] = *(const bf16x8*)&Bs[t*16 + l16][quad*8];
    #pragma unroll
    for (int ti = 0; ti < 2; ti++)
      #pragma unroll
      for (int jn = 0; jn < 4; jn++)
        acc[ti][jn] = __builtin_amdgcn_mfma_f32_16x16x32_bf16(af[ti], bfr[jn], acc[ti][jn], 0, 0, 0);
    __syncthreads();
  }

  int region = nt >> 2;   // 0=Q (n<256), 1=K, 2=V
  if (region == 0) {
    #pragma unroll
    for (int jn = 0; jn < 4; jn++) {
      int n = n0 + jn*16 + l16;
      float bv = bias[n];
      #pragma unroll
      for (int ti = 0; ti < 2; ti++) {
        int mrow = m0 + wave*32 + ti*16 + quad*4;
        #pragma unroll
        for (int r = 0; r < 4; r++)
          q[(size_t)(b0*4096 + mrow + r)*256 + n] = f2bf((acc[ti][jn][r] + bv) * SCALE_Q);
      }
    }
  } else if (region == 1) {
    #pragma unroll
    for (int jn = 0; jn < 4; jn++) {
      int n = n0 + jn*16 + l16;
      float bv = bias[n];
      #pragma unroll
      for (int ti = 0; ti < 2; ti++) {
        int mrow = m0 + wave*32 + ti*16 + quad*4;
        #pragma unroll
        for (int r = 0; r < 4; r++)
          kbuf[(size_t)(b0*4096 + mrow + r)*256 + (n - 256)] = f2bf(acc[ti][jn][r] + bv);
      }
    }
  } else {
    int hh = nt - 8;                 // one head per 64-wide tile
    int b_loc = m0 >> 12;
    #pragma unroll
    for (int jn = 0; jn < 4; jn++) {
      int n = n0 + jn*16 + l16;
      float bv = bias[n];
      int drow = jn*16 + l16;        // d within head (0..63)
      #pragma unroll
      for (int ti = 0; ti < 2; ti++) {
        int tcol = wave*32 + ti*16 + quad*4;
        uint2 w;
        w.x = pack_rn(acc[ti][jn][0] + bv, acc[ti][jn][1] + bv);
        w.y = pack_rn(acc[ti][jn][2] + bv, acc[ti][jn][3] + bv);
        *(uint2*)&Lt[drow][tcol] = w;
      }
    }
    __syncthreads();
    size_t vb_ = ((size_t)((b0 + b_loc)*4 + hh)*64)*4096 + (size_t)(m0 & 4095);
    for (int idx = tid; idx < 1024; idx += 256) {
      int dd = idx >> 4, toff = (idx & 15)*8;
      *(uint4*)(vt + vb_ + (size_t)dd*4096 + toff) = *(const uint4*)&Lt[dd][toff];
    }
  }
}

// -------- flash attention v6b: 128-key tiles, register prefetch, and
//          __launch_bounds__(256,2) so the prefetch regs are NOT spilled
//          (round 9: default bounds capped VGPR=96 -> 382 MB scratch traffic).
// q[tok][256] (pre-scaled by 0.125*log2e), k[tok][256], vt[bh][d][tok].
// O overwrites q in place (disjoint rows/cols per block -> race-free).
__global__ __launch_bounds__(256, 2)
void attn(ushort_t* __restrict__ q, const ushort_t* __restrict__ k,
          const ushort_t* __restrict__ vt) {
  int blk = blockIdx.x;            // nb*128 = bl x h(4) x it(32)
  int it = blk & 31;
  int h  = (blk >> 5) & 3;
  int b  = blk >> 7;
  int i0 = it * 128;
  int tid = threadIdx.x;
  int wave = tid >> 6, lane = tid & 63, quad = lane >> 4, l16 = lane & 15;

  __shared__ ushort_t Ks[128][72];    // [j][d]
  __shared__ ushort_t Vs[64][136];    // [d][j]
  __shared__ ushort_t Ps[4][16][72];  // per-wave P tile [i(16)][j(64)]

  ushort_t* qbase = q + (size_t)(b*4096 + i0)*256 + h*64;
  const ushort_t* kbase = k + (size_t)(b*4096)*256 + h*64;
  const ushort_t* vbase = vt + (size_t)(b*4 + h)*64*4096;

  // Q fragments direct from global: row wave*32+t*16+l16, col kk*32+quad*8
  bf16x8 qa[2][2];
  #pragma unroll
  for (int t = 0; t < 2; t++)
    #pragma unroll
    for (int kk = 0; kk < 2; kk++) {
      uint4 u = *(const uint4*)(qbase + (size_t)(wave*32 + t*16 + l16)*256 + kk*32 + quad*8);
      qa[t][kk] = *(const bf16x8*)&u;
    }

  bf16x8 ones;
  #pragma unroll
  for (int e = 0; e < 8; e++) ones[e] = (short)0x3F80;   // bf16 1.0

  f32x4 o_acc[2][4];   // O^T frags: lane=i, reg=d
  f32x4 l_acc[2];
  #pragma unroll
  for (int t = 0; t < 2; t++) {
    l_acc[t] = (f32x4){0.f,0.f,0.f,0.f};
    #pragma unroll
    for (int d = 0; d < 4; d++) o_acc[t][d] = (f32x4){0.f,0.f,0.f,0.f};
  }

  int sj = tid >> 3, sseg = (tid & 7)*8;   // staging: sj in [0,32), sseg 8-col
  uint4 rk[4], rv[4];
  #define LOADT(JT) { int j0n = (JT)*128; \
    rk[0] = *(const uint4*)(kbase + (size_t)(j0n + sj      )*256 + sseg); \
    rk[1] = *(const uint4*)(kbase + (size_t)(j0n + sj + 32 )*256 + sseg); \
    rk[2] = *(const uint4*)(kbase + (size_t)(j0n + sj + 64 )*256 + sseg); \
    rk[3] = *(const uint4*)(kbase + (size_t)(j0n + sj + 96 )*256 + sseg); \
    rv[0] = *(const uint4*)(vbase + (size_t)(sj     )*4096 + j0n + sseg); \
    rv[1] = *(const uint4*)(vbase + (size_t)(sj     )*4096 + j0n + 64 + sseg); \
    rv[2] = *(const uint4*)(vbase + (size_t)(sj + 32)*4096 + j0n + sseg); \
    rv[3] = *(const uint4*)(vbase + (size_t)(sj + 32)*4096 + j0n + 64 + sseg); }
  #define WRITET() { \
    *(uint4*)&Ks[sj      ][sseg] = rk[0]; \
    *(uint4*)&Ks[sj + 32 ][sseg] = rk[1]; \
    *(uint4*)&Ks[sj + 64 ][sseg] = rk[2]; \
    *(uint4*)&Ks[sj + 96 ][sseg] = rk[3]; \
    *(uint4*)&Vs[sj     ][sseg] = rv[0]; \
    *(uint4*)&Vs[sj     ][64 + sseg] = rv[1]; \
    *(uint4*)&Vs[sj + 32][sseg] = rv[2]; \
    *(uint4*)&Vs[sj + 32][64 + sseg] = rv[3]; }

  LOADT(0); WRITET();
  __syncthreads();

  for (int jt = 0; jt < 32; jt++) {
    if (jt < 31) LOADT(jt + 1);    // next 128-key tile in flight

    #pragma unroll
    for (int sub = 0; sub < 2; sub++) {
      int jb = sub * 64;
      bf16x8 kb[4][2], vb[4][2];
      #pragma unroll
      for (int jn = 0; jn < 4; jn++)
        #pragma unroll
        for (int kk = 0; kk < 2; kk++) {
          kb[jn][kk] = *(const bf16x8*)&Ks[jb + jn*16 + l16][kk*32 + quad*8];
          vb[jn][kk] = *(const bf16x8*)&Vs[jn*16 + l16][jb + kk*32 + quad*8];
        }

      #pragma unroll
      for (int t = 0; t < 2; t++) {
        // S^T frags: C[j=quad*4+r][i=l16]; acc pre-biased with -16*log2e
        f32x4 s[4];
        #pragma unroll
        for (int jn = 0; jn < 4; jn++) {
          f32x4 a4 = (f32x4){-EXP_BIAS, -EXP_BIAS, -EXP_BIAS, -EXP_BIAS};
          #pragma unroll
          for (int kk = 0; kk < 2; kk++)
            a4 = __builtin_amdgcn_mfma_f32_16x16x32_bf16(kb[jn][kk], qa[t][kk], a4, 0, 0, 0);
          s[jn] = a4;
        }
        // exp, pack, b64 write: Ps[wave][i=l16][j=jn*16+quad*4..+3]
        #pragma unroll
        for (int jn = 0; jn < 4; jn++) {
          float p0 = __builtin_exp2f(s[jn][0]);
          float p1 = __builtin_exp2f(s[jn][1]);
          float p2 = __builtin_exp2f(s[jn][2]);
          float p3 = __builtin_exp2f(s[jn][3]);
          uint2 w;
          w.x = pack_trunc(p0, p1);
          w.y = pack_trunc(p2, p3);
          *(uint2*)&Ps[wave][l16][jn*16 + quad*4] = w;
        }
        // Ps wave-private: same-wave DS ordering (lgkmcnt) suffices.
        bf16x8 pa[2];
        #pragma unroll
        for (int kk = 0; kk < 2; kk++)
          pa[kk] = *(const bf16x8*)&Ps[wave][l16][kk*32 + quad*8];
        // PV + l
        #pragma unroll
        for (int dn = 0; dn < 4; dn++)
          #pragma unroll
          for (int kk = 0; kk < 2; kk++)
            o_acc[t][dn] = __builtin_amdgcn_mfma_f32_16x16x32_bf16(vb[dn][kk], pa[kk], o_acc[t][dn], 0, 0, 0);
        #pragma unroll
        for (int kk = 0; kk < 2; kk++)
          l_acc[t] = __builtin_amdgcn_mfma_f32_16x16x32_bf16(ones, pa[kk], l_acc[t], 0, 0, 0);
      }
    }

    if (jt < 31) {
      __syncthreads();             // all waves done reading Ks/Vs
      WRITET();                    // tile jt+1
      __syncthreads();             // visible
    }
  }
  #undef LOADT
  #undef WRITET

  // O^T frag: lane l16 = i, quad*4+r = d -> 4 contiguous d = b64 store
  #pragma unroll
  for (int t = 0; t < 2; t++) {
    float inv = 1.f / l_acc[t][0];
    size_t row = (size_t)(b*4096 + i0 + wave*32 + t*16 + l16)*256 + h*64;
    #pragma unroll
    for (int dn = 0; dn < 4; dn++) {
      ushort4 u;
      u.x = f2bf(o_acc[t][dn][0]*inv); u.y = f2bf(o_acc[t][dn][1]*inv);
      u.z = f2bf(o_acc[t][dn][2]*inv); u.w = f2bf(o_acc[t][dn][3]*inv);
      *(ushort4*)(q + row + dn*16 + quad*4) = u;
    }
  }
}

// - GEMM2: tile 128M x 64N. out[col][o] = sum_c wp[o][c]*O[col][c]+bias+resid
// O lives in q buffer, stride 256.
__global__ __launch_bounds__(256)
void gemm_proj(const ushort_t* __restrict__ A,    // wproj_bf [256][256]
               const ushort_t* __restrict__ Bt,   // q (O) [*][256]
               const float* __restrict__ bias, const float* __restrict__ resid,
               float* __restrict__ out, int col_base) {
  int blk = blockIdx.x;            // nb*128 = mt(2) x nt(nb*64)
  int mt = blk & 1, nt = blk >> 1;
  int m0 = mt*128, n0 = nt*64;
  int tid = threadIdx.x;
  int wave = tid >> 6, lane = tid & 63, quad = lane >> 4, l16 = lane & 15;
  __shared__ ushort_t As[128][40];
  __shared__ ushort_t Bs[64][40];
  f32x4 acc[2][4];
  #pragma unroll
  for (int i = 0; i < 2; i++)
    #pragma unroll
    for (int j = 0; j < 4; j++) acc[i][j] = (f32x4){0.f,0.f,0.f,0.f};

  for (int k0 = 0; k0 < 256; k0 += 32) {
    #pragma unroll
    for (int i = tid; i < 512; i += 256) {
      int row = i >> 2, seg = i & 3;
      *(uint4*)&As[row][seg*8] = *(const uint4*)(A + (size_t)(m0+row)*256 + k0 + seg*8);
    }
    {
      int row = tid >> 2, seg = tid & 3;
      *(uint4*)&Bs[row][seg*8] = *(const uint4*)(Bt + (size_t)(n0+row)*256 + k0 + seg*8);
    }
    __syncthreads();
    bf16x8 af[2], bfr[4];
    #pragma unroll
    for (int t = 0; t < 2; t++) af[t]  = *(const bf16x8*)&As[wave*32 + t*16 + l16][quad*8];
    #pragma unroll
    for (int t = 0; t < 4; t++) bfr[t] = *(const bf16x8*)&Bs[t*16 + l16][quad*8];
    #pragma unroll
    for (int ti = 0; ti < 2; ti++)
      #pragma unroll
      for (int jn = 0; jn < 4; jn++)
        acc[ti][jn] = __builtin_amdgcn_mfma_f32_16x16x32_bf16(af[ti], bfr[jn], acc[ti][jn], 0, 0, 0);
    __syncthreads();
  }
  #pragma unroll
  for (int jn = 0; jn < 4; jn++) {
    int col = col_base + n0 + jn*16 + l16;
    int bb = col >> 12;
    int np = col & 4095;
    #pragma unroll
    for (int ti = 0; ti < 2; ti++) {
      int o = m0 + wave*32 + ti*16 + quad*4;
      #pragma unroll
      for (int r = 0; r < 4; r++) {
        int oo = o + r;
        size_t addr = ((size_t)(bb*256 + oo))*4096 + np;
        out[addr] = acc[ti][jn][r] + bias[oo] + resid[addr];
      }
    }
  }
}

extern "C" void kernel_launch(void* const* d_in, const int* in_sizes, int n_in,
                              void* d_out, int out_size, void* d_ws, size_t ws_size,
                              hipStream_t stream) {
  const float* x      = (const float*)d_in[0];
  const float* gamma  = (const float*)d_in[1];
  const float* beta   = (const float*)d_in[2];
  const float* w_qkv  = (const float*)d_in[3];
  const float* b_qkv  = (const float*)d_in[4];
  const float* w_proj = (const float*)d_in[5];
  const float* b_proj = (const float*)d_in[6];
  float* out = (float*)d_out;

  char* ws = (char*)d_ws;
  float*  stats    = (float*)ws;                   // 256 B
  float2* partial  = (float2*)(ws + 1024);         // 2048 B
  ushort_t* wqkv_bf  = (ushort_t*)(ws + 4096);     // 393216 B
  ushort_t* wproj_bf = (ushort_t*)(ws + 397312);   // 131072 B
  char* big = ws + 528384;

  gn_stats1<<<dim3(256), dim3(256), 0, stream>>>(x, partial);
  gn_stats2<<<dim3(1), dim3(64), 0, stream>>>(partial, stats);
  wconv2<<<dim3(256), dim3(256), 0, stream>>>(w_qkv, w_proj, wqkv_bf, wproj_bf);

  // Full path: q 8.39M + k 8.39M + vt 8.39M + xn(nb=2) 4.19M = 29,888,512 B.
  if (ws_size >= (size_t)528384 + 3*(size_t)8388608 + (size_t)4194304) {
    ushort_t* q    = (ushort_t*)big;
    ushort_t* kbuf = (ushort_t*)(big + (size_t)8388608);
    ushort_t* vt   = (ushort_t*)(big + (size_t)16777216);
    ushort_t* xn   = (ushort_t*)(big + (size_t)25165824);
    for (int c = 0; c < 2; c++) {
      int b0 = c * 2;
      gn_apply_t<<<dim3(256), dim3(256), 0, stream>>>(x, stats, gamma, beta, xn, b0);
      gemm_qkv<<<dim3(768), dim3(256), 0, stream>>>(xn, wqkv_bf, b_qkv, q, kbuf, vt, b0);
    }
    attn<<<dim3(512), dim3(256), 0, stream>>>(q, kbuf, vt);
    gemm_proj<<<dim3(512), dim3(256), 0, stream>>>(wproj_bf, q, b_proj, x, out, 0);
  } else {
    // Per-batch fallback: 4 x 2.1M = 8.4M after fixed region.
    ushort_t* q_c  = (ushort_t*)big;
    ushort_t* k_c  = (ushort_t*)(big + (size_t)2097152);
    ushort_t* vt_c = (ushort_t*)(big + (size_t)4194304);
    ushort_t* xn_c = (ushort_t*)(big + (size_t)6291456);
    for (int b0 = 0; b0 < 4; b0++) {
      gn_apply_t<<<dim3(128), dim3(256), 0, stream>>>(x, stats, gamma, beta, xn_c, b0);
      gemm_qkv<<<dim3(384), dim3(256), 0, stream>>>(xn_c, wqkv_bf, b_qkv, q_c, k_c, vt_c, 0);
      attn<<<dim3(128), dim3(256), 0, stream>>>(q_c, k_c, vt_c);
      gemm_proj<<<dim3(128), dim3(256), 0, stream>>>(wproj_bf, q_c, b_proj, x, out, b0*4096);
    }
  }
}

// Round 11
// 256.125 us; speedup vs baseline: 1.4174x; 1.1396x over previous
//
#include <hip/hip_runtime.h>
#include <stdint.h>

typedef unsigned short ushort_t;
typedef __attribute__((ext_vector_type(8))) short bf16x8;   // 8 bf16 = 4 VGPRs
typedef __attribute__((ext_vector_type(4))) float f32x4;

__device__ __forceinline__ ushort_t f2bf(float f) {
  union { float f; unsigned u; } v; v.f = f;
  unsigned r = v.u + 0x7fffu + ((v.u >> 16) & 1u);
  return (ushort_t)(r >> 16);
}
__device__ __forceinline__ unsigned bfbits(float f) {
  union { float f; unsigned u; } v; v.f = f; return v.u;
}
// pack two floats' bf16 truncations: [hi.bf16 : lo.bf16]
__device__ __forceinline__ unsigned pack_trunc(float lo, float hi) {
#if __has_builtin(__builtin_amdgcn_perm)
  return __builtin_amdgcn_perm(bfbits(hi), bfbits(lo), 0x07060302u);
#else
  return (bfbits(lo) >> 16) | (bfbits(hi) & 0xffff0000u);
#endif
}
__device__ __forceinline__ unsigned pack_rn(float lo, float hi) {
  return (unsigned)f2bf(lo) | ((unsigned)f2bf(hi) << 16);
}

#define SCALE_Q 0.18033688011112042f   /* 0.125 * log2(e) */
#define EXP_BIAS 23.083109273961734f   /* 16 * log2(e) */

// ---------- GroupNorm stats stage 1: 256 blocks x 16384 floats -------------
__global__ __launch_bounds__(256)
void gn_stats1(const float* __restrict__ x, float2* __restrict__ partial) {
  int blk = blockIdx.x, tid = threadIdx.x;
  const float* base = x + (size_t)blk * 16384;
  float s = 0.f, ss = 0.f;
  for (int i = tid * 4; i < 16384; i += 1024) {
    float4 v = *(const float4*)(base + i);
    s  += v.x + v.y + v.z + v.w;
    ss += v.x*v.x + v.y*v.y + v.z*v.z + v.w*v.w;
  }
  __shared__ float rs[256], rss[256];
  rs[tid] = s; rss[tid] = ss;
  __syncthreads();
  for (int off = 128; off > 0; off >>= 1) {
    if (tid < off) { rs[tid] += rs[tid+off]; rss[tid] += rss[tid+off]; }
    __syncthreads();
  }
  if (tid == 0) partial[blk] = make_float2(rs[0], rss[0]);
}

// ---------- GroupNorm stats stage 2: reduce 8 partials per (b,g) -----------
__global__ __launch_bounds__(64)
void gn_stats2(const float2* __restrict__ partial, float* __restrict__ stats) {
  int g = threadIdx.x;
  if (g < 32) {
    float s = 0.f, ss = 0.f;
    #pragma unroll
    for (int k = 0; k < 8; k++) { float2 p = partial[g*8 + k]; s += p.x; ss += p.y; }
    float mean = s * (1.f/131072.f);
    float var  = ss * (1.f/131072.f) - mean*mean;
    stats[g*2]   = mean;
    stats[g*2+1] = rsqrtf(var + 1e-5f);
  }
}

// -- normalize+transpose: x[b][c][n] -> xn_t[(b-b0)*4096+n][c] (bf16 chunk) -
__global__ __launch_bounds__(256)
void gn_apply_t(const float* __restrict__ x, const float* __restrict__ stats,
                const float* __restrict__ gamma, const float* __restrict__ beta,
                ushort_t* __restrict__ xn_t, int b0) {
  int blk = blockIdx.x;            // nb*128 = bl x nt(16) x ct(8)
  int tid = threadIdx.x;
  int ct = blk & 7;
  int nt = (blk >> 3) & 15;
  int bl = blk >> 7;               // local batch in chunk
  int b  = b0 + bl;                // global batch
  int c0 = ct * 32;                // one 32-ch group per tile (group == ct)
  float mean = stats[(b*8 + ct)*2];
  float rstd = stats[(b*8 + ct)*2 + 1];
  __shared__ ushort_t Ls[32][264];
  for (int idx = tid; idx < 32*64; idx += 256) {
    int cc = idx >> 6, seg = idx & 63;
    float ga = gamma[c0+cc], be = beta[c0+cc];
    float a = rstd * ga;
    float bb = be - mean * a;
    float4 v = *(const float4*)(x + ((size_t)(b*256 + c0 + cc))*4096 + nt*256 + seg*4);
    ushort4 t4 = make_ushort4(f2bf(v.x*a+bb), f2bf(v.y*a+bb), f2bf(v.z*a+bb), f2bf(v.w*a+bb));
    *(ushort4*)&Ls[cc][seg*4] = t4;
  }
  __syncthreads();
  for (int idx = tid; idx < 256*4; idx += 256) {
    int n = idx >> 2, seg = idx & 3;
    union { ushort_t u[8]; uint4 v; } pk;
    #pragma unroll
    for (int e = 0; e < 8; e++) pk.u[e] = Ls[seg*8 + e][n];
    *(uint4*)(xn_t + ((size_t)(bl*4096 + nt*256 + n))*256 + c0 + seg*8) = pk.v;
  }
}

// ------- fp32 -> bf16 weight convert, both weight tensors in one launch ----
__global__ __launch_bounds__(256)
void wconv2(const float* __restrict__ wq, const float* __restrict__ wp,
            ushort_t* __restrict__ oq, ushort_t* __restrict__ op) {
  int blk = blockIdx.x;            // 0-191: qkv (196608), 192-255: proj (65536)
  const float* w; ushort_t* o; int i;
  if (blk < 192) { w = wq; o = oq; i = blk*256 + threadIdx.x; }
  else           { w = wp; o = op; i = (blk-192)*256 + threadIdx.x; }
  float4 v = *(const float4*)(w + (size_t)i*4);
  *(ushort4*)(o + (size_t)i*4) = make_ushort4(f2bf(v.x), f2bf(v.y), f2bf(v.z), f2bf(v.w));
}

// ------- GEMM1: tile 128M x 64N. Q->q[tok][256] (scaled), K->k[tok][256],
//         V -> vt[b*4+h][d][tok] (transposed through LDS, one head/tile).
__global__ __launch_bounds__(256)
void gemm_qkv(const ushort_t* __restrict__ A, const ushort_t* __restrict__ Bt,
              const float* __restrict__ bias, ushort_t* __restrict__ q,
              ushort_t* __restrict__ kbuf, ushort_t* __restrict__ vt, int b0) {
  int blk = blockIdx.x;            // (nb*32)*12 = mt x nt(12)
  int nt = blk % 12, mt = blk / 12;
  int m0 = mt*128, n0 = nt*64;
  int tid = threadIdx.x;
  int wave = tid >> 6, lane = tid & 63, quad = lane >> 4, l16 = lane & 15;
  __shared__ ushort_t As[128][40];
  __shared__ ushort_t Bs[64][40];
  __shared__ ushort_t Lt[64][136];   // V transpose tile [d][tok]
  f32x4 acc[2][4];
  #pragma unroll
  for (int i = 0; i < 2; i++)
    #pragma unroll
    for (int j = 0; j < 4; j++) acc[i][j] = (f32x4){0.f,0.f,0.f,0.f};

  for (int k0 = 0; k0 < 256; k0 += 32) {
    #pragma unroll
    for (int i = tid; i < 512; i += 256) {
      int row = i >> 2, seg = i & 3;
      *(uint4*)&As[row][seg*8] = *(const uint4*)(A + (size_t)(m0+row)*256 + k0 + seg*8);
    }
    {
      int row = tid >> 2, seg = tid & 3;
      *(uint4*)&Bs[row][seg*8] = *(const uint4*)(Bt + (size_t)(n0+row)*256 + k0 + seg*8);
    }
    __syncthreads();
    bf16x8 af[2], bfr[4];
    #pragma unroll
    for (int t = 0; t < 2; t++) af[t]  = *(const bf16x8*)&As[wave*32 + t*16 + l16][quad*8];
    #pragma unroll
    for (int t = 0; t < 4; t++) bfr[t] = *(const bf16x8*)&Bs[t*16 + l16][quad*8];
    #pragma unroll
    for (int ti = 0; ti < 2; ti++)
      #pragma unroll
      for (int jn = 0; jn < 4; jn++)
        acc[ti][jn] = __builtin_amdgcn_mfma_f32_16x16x32_bf16(af[ti], bfr[jn], acc[ti][jn], 0, 0, 0);
    __syncthreads();
  }

  int region = nt >> 2;   // 0=Q (n<256), 1=K, 2=V
  if (region == 0) {
    #pragma unroll
    for (int jn = 0; jn < 4; jn++) {
      int n = n0 + jn*16 + l16;
      float bv = bias[n];
      #pragma unroll
      for (int ti = 0; ti < 2; ti++) {
        int mrow = m0 + wave*32 + ti*16 + quad*4;
        #pragma unroll
        for (int r = 0; r < 4; r++)
          q[(size_t)(b0*4096 + mrow + r)*256 + n] = f2bf((acc[ti][jn][r] + bv) * SCALE_Q);
      }
    }
  } else if (region == 1) {
    #pragma unroll
    for (int jn = 0; jn < 4; jn++) {
      int n = n0 + jn*16 + l16;
      float bv = bias[n];
      #pragma unroll
      for (int ti = 0; ti < 2; ti++) {
        int mrow = m0 + wave*32 + ti*16 + quad*4;
        #pragma unroll
        for (int r = 0; r < 4; r++)
          kbuf[(size_t)(b0*4096 + mrow + r)*256 + (n - 256)] = f2bf(acc[ti][jn][r] + bv);
      }
    }
  } else {
    int hh = nt - 8;                 // one head per 64-wide tile
    int b_loc = m0 >> 12;
    #pragma unroll
    for (int jn = 0; jn < 4; jn++) {
      int n = n0 + jn*16 + l16;
      float bv = bias[n];
      int drow = jn*16 + l16;        // d within head (0..63)
      #pragma unroll
      for (int ti = 0; ti < 2; ti++) {
        int tcol = wave*32 + ti*16 + quad*4;
        uint2 w;
        w.x = pack_rn(acc[ti][jn][0] + bv, acc[ti][jn][1] + bv);
        w.y = pack_rn(acc[ti][jn][2] + bv, acc[ti][jn][3] + bv);
        *(uint2*)&Lt[drow][tcol] = w;
      }
    }
    __syncthreads();
    size_t vb_ = ((size_t)((b0 + b_loc)*4 + hh)*64)*4096 + (size_t)(m0 & 4095);
    for (int idx = tid; idx < 1024; idx += 256) {
      int dd = idx >> 4, toff = (idx & 15)*8;
      *(uint4*)(vt + vb_ + (size_t)dd*4096 + toff) = *(const uint4*)&Lt[dd][toff];
    }
  }
}

// -------- flash attention v7: 128-key tiles, LDS double-buffer, ONE barrier
//          per 128 keys; staging split K-then-V so prefetch regs live only
//          one 64-key sub-tile each (16 VGPRs peak -> no scratch spill).
// q[tok][256] (pre-scaled by 0.125*log2e), k[tok][256], vt[bh][d][tok].
// O overwrites q in place (disjoint rows/cols per block -> race-free).
__global__ __launch_bounds__(256, 2)
void attn(ushort_t* __restrict__ q, const ushort_t* __restrict__ k,
          const ushort_t* __restrict__ vt) {
  int blk = blockIdx.x;            // nb*128 = bl x h(4) x it(32)
  int it = blk & 31;
  int h  = (blk >> 5) & 3;
  int b  = blk >> 7;
  int i0 = it * 128;
  int tid = threadIdx.x;
  int wave = tid >> 6, lane = tid & 63, quad = lane >> 4, l16 = lane & 15;

  __shared__ ushort_t Ks[2][128][68];  // [j][d], pad->stride 136B (2 banks)
  __shared__ ushort_t Vs[2][64][132];  // [d][j], pad->stride 264B (2 banks)
  __shared__ ushort_t Ps[4][16][72];   // per-wave P tile [i(16)][j(64)]

  ushort_t* qbase = q + (size_t)(b*4096 + i0)*256 + h*64;
  const ushort_t* kbase = k + (size_t)(b*4096)*256 + h*64;
  const ushort_t* vbase = vt + (size_t)(b*4 + h)*64*4096;

  // Q fragments direct from global: row wave*32+t*16+l16, col kk*32+quad*8
  bf16x8 qa[2][2];
  #pragma unroll
  for (int t = 0; t < 2; t++)
    #pragma unroll
    for (int kk = 0; kk < 2; kk++) {
      uint4 u = *(const uint4*)(qbase + (size_t)(wave*32 + t*16 + l16)*256 + kk*32 + quad*8);
      qa[t][kk] = *(const bf16x8*)&u;
    }

  bf16x8 ones;
  #pragma unroll
  for (int e = 0; e < 8; e++) ones[e] = (short)0x3F80;   // bf16 1.0

  f32x4 o_acc[2][4];   // O^T frags: lane=i, reg=d
  f32x4 l_acc[2];
  #pragma unroll
  for (int t = 0; t < 2; t++) {
    l_acc[t] = (f32x4){0.f,0.f,0.f,0.f};
    #pragma unroll
    for (int d = 0; d < 4; d++) o_acc[t][d] = (f32x4){0.f,0.f,0.f,0.f};
  }

  int sj = tid >> 3, sseg = (tid & 7)*8;   // staging: sj in [0,32), sseg 8-col
  uint4 rk[4], rv[4];
  #define LOADK(JT) { int j0n = (JT)*128; \
    rk[0] = *(const uint4*)(kbase + (size_t)(j0n + sj      )*256 + sseg); \
    rk[1] = *(const uint4*)(kbase + (size_t)(j0n + sj + 32 )*256 + sseg); \
    rk[2] = *(const uint4*)(kbase + (size_t)(j0n + sj + 64 )*256 + sseg); \
    rk[3] = *(const uint4*)(kbase + (size_t)(j0n + sj + 96 )*256 + sseg); }
  #define LOADV(JT) { int j0n = (JT)*128; \
    rv[0] = *(const uint4*)(vbase + (size_t)(sj     )*4096 + j0n + sseg); \
    rv[1] = *(const uint4*)(vbase + (size_t)(sj     )*4096 + j0n + 64 + sseg); \
    rv[2] = *(const uint4*)(vbase + (size_t)(sj + 32)*4096 + j0n + sseg); \
    rv[3] = *(const uint4*)(vbase + (size_t)(sj + 32)*4096 + j0n + 64 + sseg); }
  #define WRITEK(BI) { \
    *(uint4*)&Ks[BI][sj      ][sseg] = rk[0]; \
    *(uint4*)&Ks[BI][sj + 32 ][sseg] = rk[1]; \
    *(uint4*)&Ks[BI][sj + 64 ][sseg] = rk[2]; \
    *(uint4*)&Ks[BI][sj + 96 ][sseg] = rk[3]; }
  #define WRITEV(BI) { \
    *(uint4*)&Vs[BI][sj     ][sseg] = rv[0]; \
    *(uint4*)&Vs[BI][sj     ][64 + sseg] = rv[1]; \
    *(uint4*)&Vs[BI][sj + 32][sseg] = rv[2]; \
    *(uint4*)&Vs[BI][sj + 32][64 + sseg] = rv[3]; }

  // compute one 64-key sub-tile (jb = 0 or 64) against buffer BI
  #define COMPUTE_SUB(BI, jb) { \
    bf16x8 kb[4][2], vb[4][2]; \
    _Pragma("unroll") \
    for (int jn = 0; jn < 4; jn++) \
      _Pragma("unroll") \
      for (int kk = 0; kk < 2; kk++) { \
        kb[jn][kk] = *(const bf16x8*)&Ks[BI][(jb) + jn*16 + l16][kk*32 + quad*8]; \
        vb[jn][kk] = *(const bf16x8*)&Vs[BI][jn*16 + l16][(jb) + kk*32 + quad*8]; \
      } \
    _Pragma("unroll") \
    for (int t = 0; t < 2; t++) { \
      f32x4 s[4]; \
      _Pragma("unroll") \
      for (int jn = 0; jn < 4; jn++) { \
        f32x4 a4 = (f32x4){-EXP_BIAS, -EXP_BIAS, -EXP_BIAS, -EXP_BIAS}; \
        _Pragma("unroll") \
        for (int kk = 0; kk < 2; kk++) \
          a4 = __builtin_amdgcn_mfma_f32_16x16x32_bf16(kb[jn][kk], qa[t][kk], a4, 0, 0, 0); \
        s[jn] = a4; \
      } \
      _Pragma("unroll") \
      for (int jn = 0; jn < 4; jn++) { \
        float p0 = __builtin_exp2f(s[jn][0]); \
        float p1 = __builtin_exp2f(s[jn][1]); \
        float p2 = __builtin_exp2f(s[jn][2]); \
        float p3 = __builtin_exp2f(s[jn][3]); \
        uint2 w; \
        w.x = pack_trunc(p0, p1); \
        w.y = pack_trunc(p2, p3); \
        *(uint2*)&Ps[wave][l16][jn*16 + quad*4] = w; \
      } \
      bf16x8 pa[2]; \
      _Pragma("unroll") \
      for (int kk = 0; kk < 2; kk++) \
        pa[kk] = *(const bf16x8*)&Ps[wave][l16][kk*32 + quad*8]; \
      _Pragma("unroll") \
      for (int dn = 0; dn < 4; dn++) \
        _Pragma("unroll") \
        for (int kk = 0; kk < 2; kk++) \
          o_acc[t][dn] = __builtin_amdgcn_mfma_f32_16x16x32_bf16(vb[dn][kk], pa[kk], o_acc[t][dn], 0, 0, 0); \
      _Pragma("unroll") \
      for (int kk = 0; kk < 2; kk++) \
        l_acc[t] = __builtin_amdgcn_mfma_f32_16x16x32_bf16(ones, pa[kk], l_acc[t], 0, 0, 0); \
    } }

  LOADK(0); LOADV(0); WRITEK(0); WRITEV(0);
  __syncthreads();

  for (int jt = 0; jt < 32; jt++) {
    int cur = jt & 1;
    if (jt < 31) LOADK(jt + 1);       // K loads age across sub0
    COMPUTE_SUB(cur, 0);
    if (jt < 31) { WRITEK(cur ^ 1); LOADV(jt + 1); }   // V loads age across sub1
    COMPUTE_SUB(cur, 64);
    if (jt < 31) WRITEV(cur ^ 1);
    __syncthreads();                  // single barrier: nxt written, cur reads done
  }
  #undef LOADK
  #undef LOADV
  #undef WRITEK
  #undef WRITEV
  #undef COMPUTE_SUB

  // O^T frag: lane l16 = i, quad*4+r = d -> 4 contiguous d = b64 store
  #pragma unroll
  for (int t = 0; t < 2; t++) {
    float inv = 1.f / l_acc[t][0];
    size_t row = (size_t)(b*4096 + i0 + wave*32 + t*16 + l16)*256 + h*64;
    #pragma unroll
    for (int dn = 0; dn < 4; dn++) {
      ushort4 u;
      u.x = f2bf(o_acc[t][dn][0]*inv); u.y = f2bf(o_acc[t][dn][1]*inv);
      u.z = f2bf(o_acc[t][dn][2]*inv); u.w = f2bf(o_acc[t][dn][3]*inv);
      *(ushort4*)(q + row + dn*16 + quad*4) = u;
    }
  }
}

// - GEMM2: tile 128M x 64N. out[col][o] = sum_c wp[o][c]*O[col][c]+bias+resid
// O lives in q buffer, stride 256.
__global__ __launch_bounds__(256)
void gemm_proj(const ushort_t* __restrict__ A,    // wproj_bf [256][256]
               const ushort_t* __restrict__ Bt,   // q (O) [*][256]
               const float* __restrict__ bias, const float* __restrict__ resid,
               float* __restrict__ out, int col_base) {
  int blk = blockIdx.x;            // nb*128 = mt(2) x nt(nb*64)
  int mt = blk & 1, nt = blk >> 1;
  int m0 = mt*128, n0 = nt*64;
  int tid = threadIdx.x;
  int wave = tid >> 6, lane = tid & 63, quad = lane >> 4, l16 = lane & 15;
  __shared__ ushort_t As[128][40];
  __shared__ ushort_t Bs[64][40];
  f32x4 acc[2][4];
  #pragma unroll
  for (int i = 0; i < 2; i++)
    #pragma unroll
    for (int j = 0; j < 4; j++) acc[i][j] = (f32x4){0.f,0.f,0.f,0.f};

  for (int k0 = 0; k0 < 256; k0 += 32) {
    #pragma unroll
    for (int i = tid; i < 512; i += 256) {
      int row = i >> 2, seg = i & 3;
      *(uint4*)&As[row][seg*8] = *(const uint4*)(A + (size_t)(m0+row)*256 + k0 + seg*8);
    }
    {
      int row = tid >> 2, seg = tid & 3;
      *(uint4*)&Bs[row][seg*8] = *(const uint4*)(Bt + (size_t)(n0+row)*256 + k0 + seg*8);
    }
    __syncthreads();
    bf16x8 af[2], bfr[4];
    #pragma unroll
    for (int t = 0; t < 2; t++) af[t]  = *(const bf16x8*)&As[wave*32 + t*16 + l16][quad*8];
    #pragma unroll
    for (int t = 0; t < 4; t++) bfr[t] = *(const bf16x8*)&Bs[t*16 + l16][quad*8];
    #pragma unroll
    for (int ti = 0; ti < 2; ti++)
      #pragma unroll
      for (int jn = 0; jn < 4; jn++)
        acc[ti][jn] = __builtin_amdgcn_mfma_f32_16x16x32_bf16(af[ti], bfr[jn], acc[ti][jn], 0, 0, 0);
    __syncthreads();
  }
  #pragma unroll
  for (int jn = 0; jn < 4; jn++) {
    int col = col_base + n0 + jn*16 + l16;
    int bb = col >> 12;
    int np = col & 4095;
    #pragma unroll
    for (int ti = 0; ti < 2; ti++) {
      int o = m0 + wave*32 + ti*16 + quad*4;
      #pragma unroll
      for (int r = 0; r < 4; r++) {
        int oo = o + r;
        size_t addr = ((size_t)(bb*256 + oo))*4096 + np;
        out[addr] = acc[ti][jn][r] + bias[oo] + resid[addr];
      }
    }
  }
}

extern "C" void kernel_launch(void* const* d_in, const int* in_sizes, int n_in,
                              void* d_out, int out_size, void* d_ws, size_t ws_size,
                              hipStream_t stream) {
  const float* x      = (const float*)d_in[0];
  const float* gamma  = (const float*)d_in[1];
  const float* beta   = (const float*)d_in[2];
  const float* w_qkv  = (const float*)d_in[3];
  const float* b_qkv  = (const float*)d_in[4];
  const float* w_proj = (const float*)d_in[5];
  const float* b_proj = (const float*)d_in[6];
  float* out = (float*)d_out;

  char* ws = (char*)d_ws;
  float*  stats    = (float*)ws;                   // 256 B
  float2* partial  = (float2*)(ws + 1024);         // 2048 B
  ushort_t* wqkv_bf  = (ushort_t*)(ws + 4096);     // 393216 B
  ushort_t* wproj_bf = (ushort_t*)(ws + 397312);   // 131072 B
  char* big = ws + 528384;

  gn_stats1<<<dim3(256), dim3(256), 0, stream>>>(x, partial);
  gn_stats2<<<dim3(1), dim3(64), 0, stream>>>(partial, stats);
  wconv2<<<dim3(256), dim3(256), 0, stream>>>(w_qkv, w_proj, wqkv_bf, wproj_bf);

  // Full path: q 8.39M + k 8.39M + vt 8.39M + xn(nb=2) 4.19M = 29,888,512 B.
  if (ws_size >= (size_t)528384 + 3*(size_t)8388608 + (size_t)4194304) {
    ushort_t* q    = (ushort_t*)big;
    ushort_t* kbuf = (ushort_t*)(big + (size_t)8388608);
    ushort_t* vt   = (ushort_t*)(big + (size_t)16777216);
    ushort_t* xn   = (ushort_t*)(big + (size_t)25165824);
    for (int c = 0; c < 2; c++) {
      int b0 = c * 2;
      gn_apply_t<<<dim3(256), dim3(256), 0, stream>>>(x, stats, gamma, beta, xn, b0);
      gemm_qkv<<<dim3(768), dim3(256), 0, stream>>>(xn, wqkv_bf, b_qkv, q, kbuf, vt, b0);
    }
    attn<<<dim3(512), dim3(256), 0, stream>>>(q, kbuf, vt);
    gemm_proj<<<dim3(512), dim3(256), 0, stream>>>(wproj_bf, q, b_proj, x, out, 0);
  } else {
    // Per-batch fallback: 4 x 2.1M = 8.4M after fixed region.
    ushort_t* q_c  = (ushort_t*)big;
    ushort_t* k_c  = (ushort_t*)(big + (size_t)2097152);
    ushort_t* vt_c = (ushort_t*)(big + (size_t)4194304);
    ushort_t* xn_c = (ushort_t*)(big + (size_t)6291456);
    for (int b0 = 0; b0 < 4; b0++) {
      gn_apply_t<<<dim3(128), dim3(256), 0, stream>>>(x, stats, gamma, beta, xn_c, b0);
      gemm_qkv<<<dim3(384), dim3(256), 0, stream>>>(xn_c, wqkv_bf, b_qkv, q_c, k_c, vt_c, 0);
      attn<<<dim3(128), dim3(256), 0, stream>>>(q_c, k_c, vt_c);
      gemm_proj<<<dim3(128), dim3(256), 0, stream>>>(wproj_bf, q_c, b_proj, x, out, b0*4096);
    }
  }
}